// Round 9
// baseline (262.360 us; speedup 1.0000x reference)
//
#include <hip/hip_runtime.h>
#include <cstdint>
#include <cstddef>

#define NN      10000
#define NE      320000
#define FINF    2
#define HIDN    64
#define OUTN    16
#define BBATCH  4
#define TSTEPS  12
#define NBROWS  (NN * BBATCH)                    // 40000 (n-major, row = n*B + b)
#define XTN     (TSTEPS * NN * BBATCH * FINF)    // 960000
#define CAP     96                               // bucket capacity; P(deg>96) ~ 1e-18

typedef _Float16 v8h __attribute__((ext_vector_type(8)));
typedef float    v4f __attribute__((ext_vector_type(4)));

// ---------------- fused setup: transpose + bucket-scatter + param fold ------
// xAll[n][96], inner j = t*8 + b*2 + f  (n-major: SpMM gathers are contiguous)
// PP layout (floats):
//   [0)      Lzb[64][64]   = Lz_w rows 64..127  (k-major [k][j])
//   [4096)   Lrb[64][64]
//   [8192)   Lhb[64][64]
//   [12288)  W2[3][2][64]  = Wg @ Lg_top
//   [12672)  b2[3][64]     = bg @ Lg_top + Lg_b
//   [12864)  lin_w[64][16]
//   [13888)  lin_b[16]     (total 13904)
__global__ void setup_kernel(const float* __restrict__ x,
                             const int* __restrict__ src, const int* __restrict__ dst,
                             const float* __restrict__ ew,
                             int* __restrict__ cnt, float* __restrict__ degf,
                             int2* __restrict__ bucket, float* __restrict__ xAll,
                             const float* __restrict__ Wz, const float* __restrict__ bz,
                             const float* __restrict__ Wr, const float* __restrict__ br,
                             const float* __restrict__ Wh, const float* __restrict__ bh,
                             const float* __restrict__ Lz, const float* __restrict__ Lz_b,
                             const float* __restrict__ Lr, const float* __restrict__ Lr_b,
                             const float* __restrict__ Lh, const float* __restrict__ Lh_b,
                             const float* __restrict__ linw, const float* __restrict__ linb,
                             float* __restrict__ PP) {
    int idx = blockIdx.x * 256 + threadIdx.x;
    // transpose x[B][N][FIN][T] -> xAll[n][t*8 + b*2 + f]
    if (idx < XTN) {
        int n = idx / 96;
        int j = idx - n * 96;
        int t = j >> 3;
        int b = (j >> 1) & 3;
        int f = j & 1;
        xAll[idx] = x[((size_t)(b * NN + n) * FINF + f) * TSTEPS + t];
    }
    // bucket scatter by dst + weighted degree
    if (idx < NE) {
        int d = dst[idx];
        int s = src[idx];
        float w = ew[idx];
        int p = atomicAdd(&cnt[d], 1);
        if (p < CAP) {
            int2 rec;
            rec.x = s;
            rec.y = __float_as_int(w);
            bucket[d * CAP + p] = rec;
        }
        atomicAdd(&degf[d], w);
    }
    // parameter folding
    if (idx < 13904) {
        const float* Lg[3]    = {Lz, Lr, Lh};
        const float* Lbias[3] = {Lz_b, Lr_b, Lh_b};
        const float* Wg[3]    = {Wz, Wr, Wh};
        const float* bg[3]    = {bz, br, bh};
        int i = idx;
        if (i < 12288) {
            int g = i >> 12, rr = (i >> 6) & 63, j = i & 63;
            PP[i] = Lg[g][(64 + rr) * 64 + j];
        } else if (i < 12672) {
            int i2 = i - 12288;
            int g = i2 >> 7, f = (i2 >> 6) & 1, j = i2 & 63;
            float s = 0.f;
            for (int k = 0; k < 64; ++k) s = fmaf(Wg[g][f * 64 + k], Lg[g][k * 64 + j], s);
            PP[i] = s;
        } else if (i < 12864) {
            int i3 = i - 12672;
            int g = i3 >> 6, j = i3 & 63;
            float s = Lbias[g][j];
            for (int k = 0; k < 64; ++k) s = fmaf(bg[g][k], Lg[g][k * 64 + j], s);
            PP[i] = s;
        } else if (i < 13888) {
            PP[i] = linw[i - 12864];
        } else {
            PP[i] = linb[i - 13888];
        }
    }
}

// ---------------- coalesced SpMM aggregation (unchanged) ----------------
__global__ __launch_bounds__(128)
void aggregate_kernel(const float* __restrict__ xAll, const int2* __restrict__ bucket,
                      const int* __restrict__ cnt, const float* __restrict__ degf,
                      float* __restrict__ agg) {
    __shared__ float s_c[CAP];
    __shared__ int   s_src[CAP];
    const int n = blockIdx.x;
    const int tid = threadIdx.x;
    const int cntn = min(cnt[n], CAP);
    const float dn = rsqrtf(1.0f + degf[n]);
    for (int i = tid; i < cntn; i += 128) {
        int2 rec = bucket[n * CAP + i];
        int s = rec.x;
        float w = __int_as_float(rec.y);
        s_src[i] = s;
        s_c[i] = w * dn * rsqrtf(1.0f + degf[s]);
    }
    __syncthreads();
    if (tid < 96) {
        float acc = dn * dn * xAll[(size_t)n * 96 + tid];
        int i = 0;
        for (; i + 4 <= cntn; i += 4) {
            const float c0 = s_c[i],     c1 = s_c[i + 1];
            const float c2 = s_c[i + 2], c3 = s_c[i + 3];
            const float x0 = xAll[(size_t)s_src[i] * 96 + tid];
            const float x1 = xAll[(size_t)s_src[i + 1] * 96 + tid];
            const float x2 = xAll[(size_t)s_src[i + 2] * 96 + tid];
            const float x3 = xAll[(size_t)s_src[i + 3] * 96 + tid];
            acc = fmaf(c0, x0, acc);
            acc = fmaf(c1, x1, acc);
            acc = fmaf(c2, x2, acc);
            acc = fmaf(c3, x3, acc);
        }
        for (; i < cntn; ++i)
            acc = fmaf(s_c[i], xAll[(size_t)s_src[i] * 96 + tid], acc);
        const int t = tid >> 3, bf = tid & 7;
        agg[((size_t)t * NN + n) * 8 + bf] = acc;
    }
}

// ---------------- recurrent GRU (MFMA, 2-wave blocks + XOR-swizzled H) ------
// 128 thr = 2 waves; each wave owns M=16 rows; grid 1250 (4.88 blocks/CU avg,
// ~2% imbalance tail vs 23% at 625). LDS ~32.3 KB -> 4 blocks/CU (8 waves).
// H tile swizzle: H[row][k] stored at column k ^ ((row>>2)*8); per write
// instruction the four q-groups hit disjoint bank octets (2 lanes/bank = free);
// A-frag reads stay 16B-contiguous at base (q ^ (m>>2))*8 (+32 for aH1).
__device__ __forceinline__ float fsigmoid(float x) {
    return 1.0f / (1.0f + __expf(-x));
}

__global__ __launch_bounds__(128, 2)
void recurrent_kernel(const float* __restrict__ agg, const float* __restrict__ PP,
                      float* __restrict__ out) {
    __shared__ _Float16 WT[3 * 64 * 72 + 32];  // [gate][n][k<64: L | 64..66: init], pad
    __shared__ _Float16 Hm[2][16 * 72];        // per-wave H [row][k^swz], stride 72
    const int tid = threadIdx.x;
    const int w   = tid >> 6;
    const int l   = tid & 63;
    const int m   = l & 15;          // A row / B,C col within 16x16 tile
    const int q   = l >> 4;          // quad: A k-group, C row-group
    const int W0  = blockIdx.x * 32 + w * 16;   // wave's first global row
    const int n0  = (W0 >> 2) + q;   // lane's node for C-layout (4 C-rows = b)

    // stage gate weights transposed [n][k] (B-fragments)
    for (int i = tid; i < 12288; i += 128) {
        int g = i >> 12, rem = i & 4095, k = rem >> 6, n = rem & 63;
        WT[(g * 64 + n) * 72 + k] = (_Float16)PP[i];
    }
    // init rows k=64..66: W2_f0, W2_f1, b2 ; 67..71 zero
    for (int i = tid; i < 3 * 64 * 8; i += 128) {   // 1536
        int g = i >> 9, rem = i & 511, n = rem >> 3, kk = rem & 7;
        float v = 0.f;
        if (kk == 0)      v = PP[12288 + g * 128 + n];
        else if (kk == 1) v = PP[12288 + g * 128 + 64 + n];
        else if (kk == 2) v = PP[12672 + g * 64 + n];
        WT[(g * 64 + n) * 72 + 64 + kk] = (_Float16)v;
    }
    for (int i = tid; i < 32; i += 128) WT[3 * 64 * 72 + i] = (_Float16)0.f;
    __syncthreads();   // only block barrier

    // lin B-fragments + bias (small, loop-invariant)
    v8h linB0, linB1;
    #pragma unroll
    for (int i = 0; i < 8; ++i) {
        linB0[i] = (_Float16)PP[12864 + (q * 8 + i) * 16 + m];
        linB1[i] = (_Float16)PP[12864 + (32 + q * 8 + i) * 16 + m];
    }
    const float linbv = PP[13888 + m];

    _Float16* __restrict__ Hw = &Hm[w][0];
    // A-frag read base: row m, k-group q, swizzled by (m>>2)
    const _Float16* __restrict__ Ard = Hw + m * 72 + ((q ^ (m >> 2)) * 8);
    // write column swizzle for this lane's C rows (row>>2 == q)
    const int wsw = q * 8;

    float Hold[4][4];                 // fp32 H master, C-layout [ntile][reg]
    #pragma unroll
    for (int nt = 0; nt < 4; ++nt)
        #pragma unroll
        for (int r = 0; r < 4; ++r) Hold[nt][r] = 0.f;
    v8h aH0{}, aH1{};                 // A-fragments of H (zero at t=0)

    // prefetch t=0 input pair for the init A-fragment (row = W0 + m)
    float2 avc = make_float2(0.f, 0.f);
    if (q == 0) avc = *(const float2*)(agg + (size_t)(W0 + m) * 2);

    const v4f zeroc = {0.f, 0.f, 0.f, 0.f};

    for (int t = 0; t < TSTEPS; ++t) {
        float2 avn = make_float2(0.f, 0.f);
        if (q == 0 && t + 1 < TSTEPS)
            avn = *(const float2*)(agg + (size_t)(t + 1) * (NN * 8) + (size_t)(W0 + m) * 2);

        // init A-fragment: [a0, a1, 1, 0...] on q=0 lanes, else 0
        v8h aI{};
        if (q == 0) {
            aI[0] = (_Float16)avc.x;
            aI[1] = (_Float16)avc.y;
            aI[2] = (_Float16)1.0f;
        }

        // ---- Z, R: 3 chained MFMAs each (init + 2 H-chunks) per n-tile ----
        v4f accZ[4], accR[4];
        #pragma unroll
        for (int nt = 0; nt < 4; ++nt) {
            const _Float16* bz = &WT[(0 * 64 + nt * 16 + m) * 72 + q * 8];
            const _Float16* br = &WT[(1 * 64 + nt * 16 + m) * 72 + q * 8];
            accZ[nt] = __builtin_amdgcn_mfma_f32_16x16x32_f16(aI,  *(const v8h*)(bz + 64), zeroc,    0, 0, 0);
            accZ[nt] = __builtin_amdgcn_mfma_f32_16x16x32_f16(aH0, *(const v8h*)bz,        accZ[nt], 0, 0, 0);
            accZ[nt] = __builtin_amdgcn_mfma_f32_16x16x32_f16(aH1, *(const v8h*)(bz + 32), accZ[nt], 0, 0, 0);
            accR[nt] = __builtin_amdgcn_mfma_f32_16x16x32_f16(aI,  *(const v8h*)(br + 64), zeroc,    0, 0, 0);
            accR[nt] = __builtin_amdgcn_mfma_f32_16x16x32_f16(aH0, *(const v8h*)br,        accR[nt], 0, 0, 0);
            accR[nt] = __builtin_amdgcn_mfma_f32_16x16x32_f16(aH1, *(const v8h*)(br + 32), accR[nt], 0, 0, 0);
        }

        // ---- gates; write HR (fp16, swizzled) for H~'s A-operand ----
        float Z[4][4];
        #pragma unroll
        for (int nt = 0; nt < 4; ++nt) {
            #pragma unroll
            for (int r = 0; r < 4; ++r) {
                Z[nt][r] = fsigmoid(accZ[nt][r]);
                float hr = Hold[nt][r] * fsigmoid(accR[nt][r]);
                Hw[(q * 4 + r) * 72 + ((nt * 16 + m) ^ wsw)] = (_Float16)hr;
            }
        }
        __threadfence_block();   // intra-wave LDS visibility
        const v8h aP0 = *(const v8h*)Ard;
        const v8h aP1 = *(const v8h*)(Ard + 32);

        // ---- H_tilde ----
        v4f accH[4];
        #pragma unroll
        for (int nt = 0; nt < 4; ++nt) {
            const _Float16* bh = &WT[(2 * 64 + nt * 16 + m) * 72 + q * 8];
            accH[nt] = __builtin_amdgcn_mfma_f32_16x16x32_f16(aI,  *(const v8h*)(bh + 64), zeroc,    0, 0, 0);
            accH[nt] = __builtin_amdgcn_mfma_f32_16x16x32_f16(aP0, *(const v8h*)bh,        accH[nt], 0, 0, 0);
            accH[nt] = __builtin_amdgcn_mfma_f32_16x16x32_f16(aP1, *(const v8h*)(bh + 32), accH[nt], 0, 0, 0);
        }

        // ---- combine; update register H; write Hn (swizzled) ----
        #pragma unroll
        for (int nt = 0; nt < 4; ++nt) {
            #pragma unroll
            for (int r = 0; r < 4; ++r) {
                float ht = fmaf(2.0f, fsigmoid(2.0f * accH[nt][r]), -1.0f);   // tanh
                float hn = Z[nt][r] * Hold[nt][r] + (1.f - Z[nt][r]) * ht;
                Hold[nt][r] = hn;
                Hw[(q * 4 + r) * 72 + ((nt * 16 + m) ^ wsw)] = (_Float16)hn;
            }
        }
        __threadfence_block();
        aH0 = *(const v8h*)Ard;          // reused next step's Z/R
        aH1 = *(const v8h*)(Ard + 32);

        // ---- output: relu(Hn) @ lin + lin_b ----
        const v8h zz{};
        v8h r0 = __builtin_elementwise_max(aH0, zz);
        v8h r1 = __builtin_elementwise_max(aH1, zz);
        v4f accO = {linbv, linbv, linbv, linbv};
        accO = __builtin_amdgcn_mfma_f32_16x16x32_f16(r0, linB0, accO, 0, 0, 0);
        accO = __builtin_amdgcn_mfma_f32_16x16x32_f16(r1, linB1, accO, 0, 0, 0);
        #pragma unroll
        for (int r = 0; r < 4; ++r)      // C row q*4+r -> (n0, b=r), col m
            out[(((size_t)r * TSTEPS + t) * NN + n0) * 16 + m] = accO[r];

        avc = avn;
    }
}

// ---------------- launch ----------------

extern "C" void kernel_launch(void* const* d_in, const int* in_sizes, int n_in,
                              void* d_out, int out_size, void* d_ws, size_t ws_size,
                              hipStream_t stream) {
    const float* x   = (const float*)d_in[0];
    const int*   ei  = (const int*)d_in[1];
    const float* ew  = (const float*)d_in[2];
    const float* Wz  = (const float*)d_in[3];
    const float* bz  = (const float*)d_in[4];
    const float* Wr  = (const float*)d_in[5];
    const float* br  = (const float*)d_in[6];
    const float* Wh  = (const float*)d_in[7];
    const float* bh  = (const float*)d_in[8];
    const float* Lz  = (const float*)d_in[9];
    const float* Lz_b= (const float*)d_in[10];
    const float* Lr  = (const float*)d_in[11];
    const float* Lr_b= (const float*)d_in[12];
    const float* Lh  = (const float*)d_in[13];
    const float* Lh_b= (const float*)d_in[14];
    const float* lw  = (const float*)d_in[15];
    const float* lb  = (const float*)d_in[16];
    float* out = (float*)d_out;

    char* ws = (char*)d_ws;
    size_t off = 0;
    auto alloc = [&](size_t bytes) -> char* {
        char* p = ws + off;
        off += (bytes + 15) & ~(size_t)15;
        return p;
    };
    float* xAll   = (float*)alloc((size_t)XTN * 4);
    float* agg    = (float*)alloc((size_t)XTN * 4);
    float* PP     = (float*)alloc(13904 * 4);
    int2*  bucket = (int2*) alloc((size_t)NN * CAP * 8);
    int*   cnt    = (int*)  alloc(NN * 4);   // cnt and degf adjacent: one memset
    float* degf   = (float*)alloc(NN * 4);

    const int* srcp = ei;
    const int* dstp = ei + NE;

    hipMemsetAsync(cnt, 0, 2 * NN * sizeof(int), stream);   // cnt + degf
    setup_kernel<<<(XTN + 255) / 256, 256, 0, stream>>>(x, srcp, dstp, ew, cnt, degf,
                                                        bucket, xAll,
                                                        Wz, bz, Wr, br, Wh, bh,
                                                        Lz, Lz_b, Lr, Lr_b, Lh, Lh_b,
                                                        lw, lb, PP);
    aggregate_kernel<<<NN, 128, 0, stream>>>(xAll, bucket, cnt, degf, agg);
    recurrent_kernel<<<NBROWS / 32, 128, 0, stream>>>(agg, PP, out);
}

// Round 10
// 236.936 us; speedup vs baseline: 1.1073x; 1.1073x over previous
//
#include <hip/hip_runtime.h>
#include <cstdint>
#include <cstddef>

#define NN      10000
#define NE      320000
#define FINF    2
#define HIDN    64
#define OUTN    16
#define BBATCH  4
#define TSTEPS  12
#define NBROWS  (NN * BBATCH)                    // 40000 (n-major, row = n*B + b)
#define XTN     (TSTEPS * NN * BBATCH * FINF)    // 960000
#define CAP     96                               // bucket capacity; P(deg>96) ~ 1e-18

typedef _Float16 v8h __attribute__((ext_vector_type(8)));
typedef float    v4f __attribute__((ext_vector_type(4)));

// ---------------- fused setup: transpose + bucket-scatter + param fold ------
// xAll[n][96], inner j = t*8 + b*2 + f  (n-major: SpMM gathers are contiguous)
// PP layout (floats):
//   [0)      Lzb[64][64]   = Lz_w rows 64..127  (k-major [k][j])
//   [4096)   Lrb[64][64]
//   [8192)   Lhb[64][64]
//   [12288)  W2[3][2][64]  = Wg @ Lg_top
//   [12672)  b2[3][64]     = bg @ Lg_top + Lg_b
//   [12864)  lin_w[64][16]
//   [13888)  lin_b[16]     (total 13904)
__global__ void setup_kernel(const float* __restrict__ x,
                             const int* __restrict__ src, const int* __restrict__ dst,
                             const float* __restrict__ ew,
                             int* __restrict__ cnt, float* __restrict__ degf,
                             int2* __restrict__ bucket, float* __restrict__ xAll,
                             const float* __restrict__ Wz, const float* __restrict__ bz,
                             const float* __restrict__ Wr, const float* __restrict__ br,
                             const float* __restrict__ Wh, const float* __restrict__ bh,
                             const float* __restrict__ Lz, const float* __restrict__ Lz_b,
                             const float* __restrict__ Lr, const float* __restrict__ Lr_b,
                             const float* __restrict__ Lh, const float* __restrict__ Lh_b,
                             const float* __restrict__ linw, const float* __restrict__ linb,
                             float* __restrict__ PP) {
    int idx = blockIdx.x * 256 + threadIdx.x;
    // transpose x[B][N][FIN][T] -> xAll[n][t*8 + b*2 + f]
    if (idx < XTN) {
        int n = idx / 96;
        int j = idx - n * 96;
        int t = j >> 3;
        int b = (j >> 1) & 3;
        int f = j & 1;
        xAll[idx] = x[((size_t)(b * NN + n) * FINF + f) * TSTEPS + t];
    }
    // bucket scatter by dst + weighted degree
    if (idx < NE) {
        int d = dst[idx];
        int s = src[idx];
        float w = ew[idx];
        int p = atomicAdd(&cnt[d], 1);
        if (p < CAP) {
            int2 rec;
            rec.x = s;
            rec.y = __float_as_int(w);
            bucket[d * CAP + p] = rec;
        }
        atomicAdd(&degf[d], w);
    }
    // parameter folding
    if (idx < 13904) {
        const float* Lg[3]    = {Lz, Lr, Lh};
        const float* Lbias[3] = {Lz_b, Lr_b, Lh_b};
        const float* Wg[3]    = {Wz, Wr, Wh};
        const float* bg[3]    = {bz, br, bh};
        int i = idx;
        if (i < 12288) {
            int g = i >> 12, rr = (i >> 6) & 63, j = i & 63;
            PP[i] = Lg[g][(64 + rr) * 64 + j];
        } else if (i < 12672) {
            int i2 = i - 12288;
            int g = i2 >> 7, f = (i2 >> 6) & 1, j = i2 & 63;
            float s = 0.f;
            for (int k = 0; k < 64; ++k) s = fmaf(Wg[g][f * 64 + k], Lg[g][k * 64 + j], s);
            PP[i] = s;
        } else if (i < 12864) {
            int i3 = i - 12672;
            int g = i3 >> 6, j = i3 & 63;
            float s = Lbias[g][j];
            for (int k = 0; k < 64; ++k) s = fmaf(bg[g][k], Lg[g][k * 64 + j], s);
            PP[i] = s;
        } else if (i < 13888) {
            PP[i] = linw[i - 12864];
        } else {
            PP[i] = linb[i - 13888];
        }
    }
}

// ---------------- coalesced SpMM aggregation (unchanged) ----------------
__global__ __launch_bounds__(128)
void aggregate_kernel(const float* __restrict__ xAll, const int2* __restrict__ bucket,
                      const int* __restrict__ cnt, const float* __restrict__ degf,
                      float* __restrict__ agg) {
    __shared__ float s_c[CAP];
    __shared__ int   s_src[CAP];
    const int n = blockIdx.x;
    const int tid = threadIdx.x;
    const int cntn = min(cnt[n], CAP);
    const float dn = rsqrtf(1.0f + degf[n]);
    for (int i = tid; i < cntn; i += 128) {
        int2 rec = bucket[n * CAP + i];
        int s = rec.x;
        float w = __int_as_float(rec.y);
        s_src[i] = s;
        s_c[i] = w * dn * rsqrtf(1.0f + degf[s]);
    }
    __syncthreads();
    if (tid < 96) {
        float acc = dn * dn * xAll[(size_t)n * 96 + tid];
        int i = 0;
        for (; i + 4 <= cntn; i += 4) {
            const float c0 = s_c[i],     c1 = s_c[i + 1];
            const float c2 = s_c[i + 2], c3 = s_c[i + 3];
            const float x0 = xAll[(size_t)s_src[i] * 96 + tid];
            const float x1 = xAll[(size_t)s_src[i + 1] * 96 + tid];
            const float x2 = xAll[(size_t)s_src[i + 2] * 96 + tid];
            const float x3 = xAll[(size_t)s_src[i + 3] * 96 + tid];
            acc = fmaf(c0, x0, acc);
            acc = fmaf(c1, x1, acc);
            acc = fmaf(c2, x2, acc);
            acc = fmaf(c3, x3, acc);
        }
        for (; i < cntn; ++i)
            acc = fmaf(s_c[i], xAll[(size_t)s_src[i] * 96 + tid], acc);
        const int t = tid >> 3, bf = tid & 7;
        agg[((size_t)t * NN + n) * 8 + bf] = acc;
    }
}

// ---------------- recurrent GRU (MFMA, R8 geometry + corrected swizzle) -----
// 256 thr = 4 waves; each wave owns M=16 rows; grid 625 -> ALL blocks
// co-resident (4 blocks/CU x 256 CUs = 1024 slots). Barrier-free t-loop.
// H tile: stride 72 halves (36 words/row -> q-groups base-shift 16 banks);
// column XOR 16 halves when (q&2) makes the four q-group write octets
// {4r, 16+4r, 8+4r, 24+4r} pairwise disjoint -> 2 lanes/bank = free.
// A-frag read: base (q ^ ((m>>2)&2))*8 (bit-4 flip only; 16B run intact).
__device__ __forceinline__ float fsigmoid(float x) {
    return 1.0f / (1.0f + __expf(-x));
}

__global__ __launch_bounds__(256, 3)
void recurrent_kernel(const float* __restrict__ agg, const float* __restrict__ PP,
                      float* __restrict__ out) {
    __shared__ _Float16 WT[3 * 64 * 72 + 32];  // [gate][n][k<64: L | 64..66: init], pad
    __shared__ _Float16 Hm[4][16 * 72];        // per-wave H [row][col^swz], stride 72
    const int tid = threadIdx.x;
    const int w   = tid >> 6;
    const int l   = tid & 63;
    const int m   = l & 15;          // A row / B,C col within 16x16 tile
    const int q   = l >> 4;          // quad: A k-group, C row-group
    const int W0  = blockIdx.x * 64 + w * 16;   // wave's first global row
    const int n0  = (W0 >> 2) + q;   // lane's node for C-layout (4 C-rows = b)

    // stage gate weights transposed [n][k] (B-fragments)
    for (int i = tid; i < 12288; i += 256) {
        int g = i >> 12, rem = i & 4095, k = rem >> 6, n = rem & 63;
        WT[(g * 64 + n) * 72 + k] = (_Float16)PP[i];
    }
    // init rows k=64..66: W2_f0, W2_f1, b2 ; 67..71 zero
    for (int i = tid; i < 3 * 64 * 8; i += 256) {   // 1536
        int g = i >> 9, rem = i & 511, n = rem >> 3, kk = rem & 7;
        float v = 0.f;
        if (kk == 0)      v = PP[12288 + g * 128 + n];
        else if (kk == 1) v = PP[12288 + g * 128 + 64 + n];
        else if (kk == 2) v = PP[12672 + g * 64 + n];
        WT[(g * 64 + n) * 72 + 64 + kk] = (_Float16)v;
    }
    for (int i = tid; i < 32; i += 256) WT[3 * 64 * 72 + i] = (_Float16)0.f;
    __syncthreads();   // only block barrier

    // lin B-fragments + bias (small, loop-invariant)
    v8h linB0, linB1;
    #pragma unroll
    for (int i = 0; i < 8; ++i) {
        linB0[i] = (_Float16)PP[12864 + (q * 8 + i) * 16 + m];
        linB1[i] = (_Float16)PP[12864 + (32 + q * 8 + i) * 16 + m];
    }
    const float linbv = PP[13888 + m];

    _Float16* __restrict__ Hw = &Hm[w][0];
    // write column swizzle: XOR 16 halves when this lane's row-group has q&2
    const int wsw = (q & 2) << 3;                  // 0 or 16
    // A-frag read base: owner of row m used swizzle ((m>>2)&2)<<3
    const _Float16* __restrict__ Ard = Hw + m * 72 + ((q ^ ((m >> 2) & 2)) * 8);

    float Hold[4][4];                 // fp32 H master, C-layout [ntile][reg]
    #pragma unroll
    for (int nt = 0; nt < 4; ++nt)
        #pragma unroll
        for (int r = 0; r < 4; ++r) Hold[nt][r] = 0.f;
    v8h aH0{}, aH1{};                 // A-fragments of H (zero at t=0)

    // prefetch t=0 input pair for the init A-fragment (row = W0 + m)
    float2 avc = make_float2(0.f, 0.f);
    if (q == 0) avc = *(const float2*)(agg + (size_t)(W0 + m) * 2);

    const v4f zeroc = {0.f, 0.f, 0.f, 0.f};

    for (int t = 0; t < TSTEPS; ++t) {
        float2 avn = make_float2(0.f, 0.f);
        if (q == 0 && t + 1 < TSTEPS)
            avn = *(const float2*)(agg + (size_t)(t + 1) * (NN * 8) + (size_t)(W0 + m) * 2);

        // init A-fragment: [a0, a1, 1, 0...] on q=0 lanes, else 0
        v8h aI{};
        if (q == 0) {
            aI[0] = (_Float16)avc.x;
            aI[1] = (_Float16)avc.y;
            aI[2] = (_Float16)1.0f;
        }

        // ---- Z, R: 3 chained MFMAs each (init + 2 H-chunks) per n-tile ----
        v4f accZ[4], accR[4];
        #pragma unroll
        for (int nt = 0; nt < 4; ++nt) {
            const _Float16* bz = &WT[(0 * 64 + nt * 16 + m) * 72 + q * 8];
            const _Float16* br = &WT[(1 * 64 + nt * 16 + m) * 72 + q * 8];
            accZ[nt] = __builtin_amdgcn_mfma_f32_16x16x32_f16(aI,  *(const v8h*)(bz + 64), zeroc,    0, 0, 0);
            accZ[nt] = __builtin_amdgcn_mfma_f32_16x16x32_f16(aH0, *(const v8h*)bz,        accZ[nt], 0, 0, 0);
            accZ[nt] = __builtin_amdgcn_mfma_f32_16x16x32_f16(aH1, *(const v8h*)(bz + 32), accZ[nt], 0, 0, 0);
            accR[nt] = __builtin_amdgcn_mfma_f32_16x16x32_f16(aI,  *(const v8h*)(br + 64), zeroc,    0, 0, 0);
            accR[nt] = __builtin_amdgcn_mfma_f32_16x16x32_f16(aH0, *(const v8h*)br,        accR[nt], 0, 0, 0);
            accR[nt] = __builtin_amdgcn_mfma_f32_16x16x32_f16(aH1, *(const v8h*)(br + 32), accR[nt], 0, 0, 0);
        }

        // ---- gates; write HR (fp16, swizzled) for H~'s A-operand ----
        float Z[4][4];
        #pragma unroll
        for (int nt = 0; nt < 4; ++nt) {
            #pragma unroll
            for (int r = 0; r < 4; ++r) {
                Z[nt][r] = fsigmoid(accZ[nt][r]);
                float hr = Hold[nt][r] * fsigmoid(accR[nt][r]);
                Hw[(q * 4 + r) * 72 + ((nt * 16 + m) ^ wsw)] = (_Float16)hr;
            }
        }
        __threadfence_block();   // intra-wave LDS visibility
        const v8h aP0 = *(const v8h*)Ard;
        const v8h aP1 = *(const v8h*)(Ard + 32);

        // ---- H_tilde ----
        v4f accH[4];
        #pragma unroll
        for (int nt = 0; nt < 4; ++nt) {
            const _Float16* bh = &WT[(2 * 64 + nt * 16 + m) * 72 + q * 8];
            accH[nt] = __builtin_amdgcn_mfma_f32_16x16x32_f16(aI,  *(const v8h*)(bh + 64), zeroc,    0, 0, 0);
            accH[nt] = __builtin_amdgcn_mfma_f32_16x16x32_f16(aP0, *(const v8h*)bh,        accH[nt], 0, 0, 0);
            accH[nt] = __builtin_amdgcn_mfma_f32_16x16x32_f16(aP1, *(const v8h*)(bh + 32), accH[nt], 0, 0, 0);
        }

        // ---- combine; update register H; write Hn (swizzled) ----
        #pragma unroll
        for (int nt = 0; nt < 4; ++nt) {
            #pragma unroll
            for (int r = 0; r < 4; ++r) {
                float ht = fmaf(2.0f, fsigmoid(2.0f * accH[nt][r]), -1.0f);   // tanh
                float hn = Z[nt][r] * Hold[nt][r] + (1.f - Z[nt][r]) * ht;
                Hold[nt][r] = hn;
                Hw[(q * 4 + r) * 72 + ((nt * 16 + m) ^ wsw)] = (_Float16)hn;
            }
        }
        __threadfence_block();
        aH0 = *(const v8h*)Ard;          // reused next step's Z/R
        aH1 = *(const v8h*)(Ard + 32);

        // ---- output: relu(Hn) @ lin + lin_b ----
        const v8h zz{};
        v8h r0 = __builtin_elementwise_max(aH0, zz);
        v8h r1 = __builtin_elementwise_max(aH1, zz);
        v4f accO = {linbv, linbv, linbv, linbv};
        accO = __builtin_amdgcn_mfma_f32_16x16x32_f16(r0, linB0, accO, 0, 0, 0);
        accO = __builtin_amdgcn_mfma_f32_16x16x32_f16(r1, linB1, accO, 0, 0, 0);
        #pragma unroll
        for (int r = 0; r < 4; ++r)      // C row q*4+r -> (n0, b=r), col m
            out[(((size_t)r * TSTEPS + t) * NN + n0) * 16 + m] = accO[r];

        avc = avn;
    }
}

// ---------------- launch ----------------

extern "C" void kernel_launch(void* const* d_in, const int* in_sizes, int n_in,
                              void* d_out, int out_size, void* d_ws, size_t ws_size,
                              hipStream_t stream) {
    const float* x   = (const float*)d_in[0];
    const int*   ei  = (const int*)d_in[1];
    const float* ew  = (const float*)d_in[2];
    const float* Wz  = (const float*)d_in[3];
    const float* bz  = (const float*)d_in[4];
    const float* Wr  = (const float*)d_in[5];
    const float* br  = (const float*)d_in[6];
    const float* Wh  = (const float*)d_in[7];
    const float* bh  = (const float*)d_in[8];
    const float* Lz  = (const float*)d_in[9];
    const float* Lz_b= (const float*)d_in[10];
    const float* Lr  = (const float*)d_in[11];
    const float* Lr_b= (const float*)d_in[12];
    const float* Lh  = (const float*)d_in[13];
    const float* Lh_b= (const float*)d_in[14];
    const float* lw  = (const float*)d_in[15];
    const float* lb  = (const float*)d_in[16];
    float* out = (float*)d_out;

    char* ws = (char*)d_ws;
    size_t off = 0;
    auto alloc = [&](size_t bytes) -> char* {
        char* p = ws + off;
        off += (bytes + 15) & ~(size_t)15;
        return p;
    };
    float* xAll   = (float*)alloc((size_t)XTN * 4);
    float* agg    = (float*)alloc((size_t)XTN * 4);
    float* PP     = (float*)alloc(13904 * 4);
    int2*  bucket = (int2*) alloc((size_t)NN * CAP * 8);
    int*   cnt    = (int*)  alloc(NN * 4);   // cnt and degf adjacent: one memset
    float* degf   = (float*)alloc(NN * 4);

    const int* srcp = ei;
    const int* dstp = ei + NE;

    hipMemsetAsync(cnt, 0, 2 * NN * sizeof(int), stream);   // cnt + degf
    setup_kernel<<<(XTN + 255) / 256, 256, 0, stream>>>(x, srcp, dstp, ew, cnt, degf,
                                                        bucket, xAll,
                                                        Wz, bz, Wr, br, Wh, bh,
                                                        Lz, Lz_b, Lr, Lr_b, Lh, Lh_b,
                                                        lw, lb, PP);
    aggregate_kernel<<<NN, 128, 0, stream>>>(xAll, bucket, cnt, degf, agg);
    recurrent_kernel<<<NBROWS / 64, 256, 0, stream>>>(agg, PP, out);
}

// Round 11
// 230.530 us; speedup vs baseline: 1.1381x; 1.0278x over previous
//
#include <hip/hip_runtime.h>
#include <cstdint>
#include <cstddef>

#define NN      10000
#define NE      320000
#define FINF    2
#define HIDN    64
#define OUTN    16
#define BBATCH  4
#define TSTEPS  12
#define NBROWS  (NN * BBATCH)                    // 40000 (n-major, row = n*B + b)
#define XTN     (TSTEPS * NN * BBATCH * FINF)    // 960000
#define CAP     96                               // bucket capacity; P(deg>96) ~ 1e-18

typedef _Float16 v8h __attribute__((ext_vector_type(8)));
typedef float    v4f __attribute__((ext_vector_type(4)));

// ---------------- fused setup: transpose + bucket-scatter + param fold ------
// xAll[n][96] fp16, inner j = t*8 + b*2 + f
// PP layout (floats):
//   [0)      Lzb[64][64]   = Lz_w rows 64..127  (k-major [k][j])
//   [4096)   Lrb[64][64]
//   [8192)   Lhb[64][64]
//   [12288)  W2[3][2][64]  = Wg @ Lg_top
//   [12672)  b2[3][64]     = bg @ Lg_top + Lg_b
//   [12864)  lin_w[64][16]
//   [13888)  lin_b[16]     (total 13904)
__global__ void setup_kernel(const float* __restrict__ x,
                             const int* __restrict__ src, const int* __restrict__ dst,
                             const float* __restrict__ ew,
                             int* __restrict__ cnt, float* __restrict__ degf,
                             int2* __restrict__ bucket, _Float16* __restrict__ xAll,
                             const float* __restrict__ Wz, const float* __restrict__ bz,
                             const float* __restrict__ Wr, const float* __restrict__ br,
                             const float* __restrict__ Wh, const float* __restrict__ bh,
                             const float* __restrict__ Lz, const float* __restrict__ Lz_b,
                             const float* __restrict__ Lr, const float* __restrict__ Lr_b,
                             const float* __restrict__ Lh, const float* __restrict__ Lh_b,
                             const float* __restrict__ linw, const float* __restrict__ linb,
                             float* __restrict__ PP) {
    int idx = blockIdx.x * 256 + threadIdx.x;
    // transpose x[B][N][FIN][T] -> xAll[n][t*8 + b*2 + f] (fp16)
    if (idx < XTN) {
        int n = idx / 96;
        int j = idx - n * 96;
        int t = j >> 3;
        int b = (j >> 1) & 3;
        int f = j & 1;
        xAll[idx] = (_Float16)x[((size_t)(b * NN + n) * FINF + f) * TSTEPS + t];
    }
    // bucket scatter by dst + weighted degree
    if (idx < NE) {
        int d = dst[idx];
        int s = src[idx];
        float w = ew[idx];
        int p = atomicAdd(&cnt[d], 1);
        if (p < CAP) {
            int2 rec;
            rec.x = s;
            rec.y = __float_as_int(w);
            bucket[d * CAP + p] = rec;
        }
        atomicAdd(&degf[d], w);
    }
    // parameter folding
    if (idx < 13904) {
        const float* Lg[3]    = {Lz, Lr, Lh};
        const float* Lbias[3] = {Lz_b, Lr_b, Lh_b};
        const float* Wg[3]    = {Wz, Wr, Wh};
        const float* bg[3]    = {bz, br, bh};
        int i = idx;
        if (i < 12288) {
            int g = i >> 12, rr = (i >> 6) & 63, j = i & 63;
            PP[i] = Lg[g][(64 + rr) * 64 + j];
        } else if (i < 12672) {
            int i2 = i - 12288;
            int g = i2 >> 7, f = (i2 >> 6) & 1, j = i2 & 63;
            float s = 0.f;
            for (int k = 0; k < 64; ++k) s = fmaf(Wg[g][f * 64 + k], Lg[g][k * 64 + j], s);
            PP[i] = s;
        } else if (i < 12864) {
            int i3 = i - 12672;
            int g = i3 >> 6, j = i3 & 63;
            float s = Lbias[g][j];
            for (int k = 0; k < 64; ++k) s = fmaf(bg[g][k], Lg[g][k * 64 + j], s);
            PP[i] = s;
        } else if (i < 13888) {
            PP[i] = linw[i - 12864];
        } else {
            PP[i] = linb[i - 13888];
        }
    }
}

// ---------------- coalesced SpMM aggregation (fp16 xAll) ----------------
__global__ __launch_bounds__(128)
void aggregate_kernel(const _Float16* __restrict__ xAll, const int2* __restrict__ bucket,
                      const int* __restrict__ cnt, const float* __restrict__ degf,
                      float* __restrict__ agg) {
    __shared__ float s_c[CAP];
    __shared__ int   s_src[CAP];
    const int n = blockIdx.x;
    const int tid = threadIdx.x;
    const int cntn = min(cnt[n], CAP);
    const float dn = rsqrtf(1.0f + degf[n]);
    for (int i = tid; i < cntn; i += 128) {
        int2 rec = bucket[n * CAP + i];
        int s = rec.x;
        float w = __int_as_float(rec.y);
        s_src[i] = s;
        s_c[i] = w * dn * rsqrtf(1.0f + degf[s]);
    }
    __syncthreads();
    if (tid < 96) {
        float acc = dn * dn * (float)xAll[(size_t)n * 96 + tid];
        int i = 0;
        for (; i + 4 <= cntn; i += 4) {
            const float c0 = s_c[i],     c1 = s_c[i + 1];
            const float c2 = s_c[i + 2], c3 = s_c[i + 3];
            const float x0 = (float)xAll[(size_t)s_src[i] * 96 + tid];
            const float x1 = (float)xAll[(size_t)s_src[i + 1] * 96 + tid];
            const float x2 = (float)xAll[(size_t)s_src[i + 2] * 96 + tid];
            const float x3 = (float)xAll[(size_t)s_src[i + 3] * 96 + tid];
            acc = fmaf(c0, x0, acc);
            acc = fmaf(c1, x1, acc);
            acc = fmaf(c2, x2, acc);
            acc = fmaf(c3, x3, acc);
        }
        for (; i < cntn; ++i)
            acc = fmaf(s_c[i], (float)xAll[(size_t)s_src[i] * 96 + tid], acc);
        const int t = tid >> 3, bf = tid & 7;
        agg[((size_t)t * NN + n) * 8 + bf] = acc;
    }
}

// ---------------- recurrent GRU (MFMA; Z/R B-fragments in REGISTERS) --------
// 256 thr = 4 waves; each wave owns M=16 rows; grid 625, all co-resident.
// Z,R gate weights live in VGPRs (loop-invariant MFMA B operands, loaded once
// from PP) -> the Z/R section (24 MFMAs) issues with ZERO LDS reads. H~ gate +
// all init rows stay in LDS (keeps VGPRs ~150 < the (256,3) cap ~170; R7
// showed what spill costs). LDS ~21 KB.
__device__ __forceinline__ float fsigmoid(float x) {
    return 1.0f / (1.0f + __expf(-x));
}

__global__ __launch_bounds__(256, 3)
void recurrent_kernel(const float* __restrict__ agg, const float* __restrict__ PP,
                      float* __restrict__ out) {
    __shared__ _Float16 WTH[64 * 72 + 32];      // H~: [n][k<64 | 64..66 init], pad
    __shared__ _Float16 WIZR[2 * 64 * 8 + 32];  // Z,R init: [g][n][0..7], pad
    __shared__ _Float16 Hm[4][16 * 72];         // per-wave H [row][col^swz]
    const int tid = threadIdx.x;
    const int w   = tid >> 6;
    const int l   = tid & 63;
    const int m   = l & 15;          // A row / B,C col within 16x16 tile
    const int q   = l >> 4;          // quad: A k-group, C row-group
    const int W0  = blockIdx.x * 64 + w * 16;   // wave's first global row
    const int n0  = (W0 >> 2) + q;   // lane's node for C-layout (4 C-rows = b)

    // ---- stage H~ gate [n][k] + init cols 64..66 ----
    for (int i = tid; i < 4096; i += 256) {
        int k = i >> 6, n = i & 63;
        WTH[n * 72 + k] = (_Float16)PP[8192 + i];
    }
    for (int i = tid; i < 64 * 8; i += 256) {
        int n = i >> 3, kk = i & 7;
        float v = 0.f;
        if (kk == 0)      v = PP[12288 + 2 * 128 + n];
        else if (kk == 1) v = PP[12288 + 2 * 128 + 64 + n];
        else if (kk == 2) v = PP[12672 + 2 * 64 + n];
        WTH[n * 72 + 64 + kk] = (_Float16)v;
    }
    for (int i = tid; i < 32; i += 256) WTH[64 * 72 + i] = (_Float16)0.f;
    // ---- stage Z,R init rows ----
    for (int i = tid; i < 2 * 64 * 8; i += 256) {
        int g = i >> 9, rem = i & 511, n = rem >> 3, kk = rem & 7;
        float v = 0.f;
        if (kk == 0)      v = PP[12288 + g * 128 + n];
        else if (kk == 1) v = PP[12288 + g * 128 + 64 + n];
        else if (kk == 2) v = PP[12672 + g * 64 + n];
        WIZR[(g * 64 + n) * 8 + kk] = (_Float16)v;
    }
    for (int i = tid; i < 32; i += 256) WIZR[1024 + i] = (_Float16)0.f;

    // ---- Z, R gate B-fragments -> REGISTERS (loop-invariant; 64 VGPRs) ----
    // B[k][n] per lane: n = nt*16+m, k = c*32 + q*8 + i ; PP gate g at g*4096+k*64+n
    v8h BZ[4][2], BR[4][2];
    #pragma unroll
    for (int nt = 0; nt < 4; ++nt) {
        #pragma unroll
        for (int c = 0; c < 2; ++c) {
            #pragma unroll
            for (int i = 0; i < 8; ++i) {
                int k = c * 32 + q * 8 + i;
                BZ[nt][c][i] = (_Float16)PP[k * 64 + nt * 16 + m];
                BR[nt][c][i] = (_Float16)PP[4096 + k * 64 + nt * 16 + m];
            }
        }
    }
    // lin B-fragments + bias
    v8h linB0, linB1;
    #pragma unroll
    for (int i = 0; i < 8; ++i) {
        linB0[i] = (_Float16)PP[12864 + (q * 8 + i) * 16 + m];
        linB1[i] = (_Float16)PP[12864 + (32 + q * 8 + i) * 16 + m];
    }
    const float linbv = PP[13888 + m];

    __syncthreads();   // only block barrier (LDS staging visible)

    _Float16* __restrict__ Hw = &Hm[w][0];
    const int wsw = (q & 2) << 3;                  // write column swizzle
    const _Float16* __restrict__ Ard = Hw + m * 72 + ((q ^ ((m >> 2) & 2)) * 8);

    float Hold[4][4];                 // fp32 H master, C-layout [ntile][reg]
    #pragma unroll
    for (int nt = 0; nt < 4; ++nt)
        #pragma unroll
        for (int r = 0; r < 4; ++r) Hold[nt][r] = 0.f;
    v8h aH0{}, aH1{};                 // A-fragments of H (zero at t=0)

    float2 avc = make_float2(0.f, 0.f);
    if (q == 0) avc = *(const float2*)(agg + (size_t)(W0 + m) * 2);

    const v4f zeroc = {0.f, 0.f, 0.f, 0.f};

    for (int t = 0; t < TSTEPS; ++t) {
        float2 avn = make_float2(0.f, 0.f);
        if (q == 0 && t + 1 < TSTEPS)
            avn = *(const float2*)(agg + (size_t)(t + 1) * (NN * 8) + (size_t)(W0 + m) * 2);

        // init A-fragment: [a0, a1, 1, 0...] on q=0 lanes, else 0
        v8h aI{};
        if (q == 0) {
            aI[0] = (_Float16)avc.x;
            aI[1] = (_Float16)avc.y;
            aI[2] = (_Float16)1.0f;
        }

        // ---- Z, R: init (LDS B) + 2 register-B MFMAs per n-tile ----
        v4f accZ[4], accR[4];
        #pragma unroll
        for (int nt = 0; nt < 4; ++nt) {
            const v8h bIz = *(const v8h*)&WIZR[(0 * 64 + nt * 16 + m) * 8 + q * 8];
            const v8h bIr = *(const v8h*)&WIZR[(1 * 64 + nt * 16 + m) * 8 + q * 8];
            accZ[nt] = __builtin_amdgcn_mfma_f32_16x16x32_f16(aI,  bIz,       zeroc,    0, 0, 0);
            accZ[nt] = __builtin_amdgcn_mfma_f32_16x16x32_f16(aH0, BZ[nt][0], accZ[nt], 0, 0, 0);
            accZ[nt] = __builtin_amdgcn_mfma_f32_16x16x32_f16(aH1, BZ[nt][1], accZ[nt], 0, 0, 0);
            accR[nt] = __builtin_amdgcn_mfma_f32_16x16x32_f16(aI,  bIr,       zeroc,    0, 0, 0);
            accR[nt] = __builtin_amdgcn_mfma_f32_16x16x32_f16(aH0, BR[nt][0], accR[nt], 0, 0, 0);
            accR[nt] = __builtin_amdgcn_mfma_f32_16x16x32_f16(aH1, BR[nt][1], accR[nt], 0, 0, 0);
        }

        // ---- gates; write HR (fp16, swizzled) for H~'s A-operand ----
        float Z[4][4];
        #pragma unroll
        for (int nt = 0; nt < 4; ++nt) {
            #pragma unroll
            for (int r = 0; r < 4; ++r) {
                Z[nt][r] = fsigmoid(accZ[nt][r]);
                float hr = Hold[nt][r] * fsigmoid(accR[nt][r]);
                Hw[(q * 4 + r) * 72 + ((nt * 16 + m) ^ wsw)] = (_Float16)hr;
            }
        }
        __threadfence_block();   // intra-wave LDS visibility
        const v8h aP0 = *(const v8h*)Ard;
        const v8h aP1 = *(const v8h*)(Ard + 32);

        // ---- H_tilde (B from LDS WTH) ----
        v4f accH[4];
        #pragma unroll
        for (int nt = 0; nt < 4; ++nt) {
            const _Float16* bh = &WTH[(nt * 16 + m) * 72 + q * 8];
            accH[nt] = __builtin_amdgcn_mfma_f32_16x16x32_f16(aI,  *(const v8h*)(bh + 64), zeroc,    0, 0, 0);
            accH[nt] = __builtin_amdgcn_mfma_f32_16x16x32_f16(aP0, *(const v8h*)bh,        accH[nt], 0, 0, 0);
            accH[nt] = __builtin_amdgcn_mfma_f32_16x16x32_f16(aP1, *(const v8h*)(bh + 32), accH[nt], 0, 0, 0);
        }

        // ---- combine; update register H; write Hn (swizzled) ----
        #pragma unroll
        for (int nt = 0; nt < 4; ++nt) {
            #pragma unroll
            for (int r = 0; r < 4; ++r) {
                float ht = fmaf(2.0f, fsigmoid(2.0f * accH[nt][r]), -1.0f);   // tanh
                float hn = Z[nt][r] * Hold[nt][r] + (1.f - Z[nt][r]) * ht;
                Hold[nt][r] = hn;
                Hw[(q * 4 + r) * 72 + ((nt * 16 + m) ^ wsw)] = (_Float16)hn;
            }
        }
        __threadfence_block();
        aH0 = *(const v8h*)Ard;          // reused next step's Z/R
        aH1 = *(const v8h*)(Ard + 32);

        // ---- output: relu(Hn) @ lin + lin_b ----
        const v8h zz{};
        v8h r0 = __builtin_elementwise_max(aH0, zz);
        v8h r1 = __builtin_elementwise_max(aH1, zz);
        v4f accO = {linbv, linbv, linbv, linbv};
        accO = __builtin_amdgcn_mfma_f32_16x16x32_f16(r0, linB0, accO, 0, 0, 0);
        accO = __builtin_amdgcn_mfma_f32_16x16x32_f16(r1, linB1, accO, 0, 0, 0);
        #pragma unroll
        for (int r = 0; r < 4; ++r)      // C row q*4+r -> (n0, b=r), col m
            out[(((size_t)r * TSTEPS + t) * NN + n0) * 16 + m] = accO[r];

        avc = avn;
    }
}

// ---------------- launch ----------------

extern "C" void kernel_launch(void* const* d_in, const int* in_sizes, int n_in,
                              void* d_out, int out_size, void* d_ws, size_t ws_size,
                              hipStream_t stream) {
    const float* x   = (const float*)d_in[0];
    const int*   ei  = (const int*)d_in[1];
    const float* ew  = (const float*)d_in[2];
    const float* Wz  = (const float*)d_in[3];
    const float* bz  = (const float*)d_in[4];
    const float* Wr  = (const float*)d_in[5];
    const float* br  = (const float*)d_in[6];
    const float* Wh  = (const float*)d_in[7];
    const float* bh  = (const float*)d_in[8];
    const float* Lz  = (const float*)d_in[9];
    const float* Lz_b= (const float*)d_in[10];
    const float* Lr  = (const float*)d_in[11];
    const float* Lr_b= (const float*)d_in[12];
    const float* Lh  = (const float*)d_in[13];
    const float* Lh_b= (const float*)d_in[14];
    const float* lw  = (const float*)d_in[15];
    const float* lb  = (const float*)d_in[16];
    float* out = (float*)d_out;

    char* ws = (char*)d_ws;
    size_t off = 0;
    auto alloc = [&](size_t bytes) -> char* {
        char* p = ws + off;
        off += (bytes + 15) & ~(size_t)15;
        return p;
    };
    _Float16* xAll = (_Float16*)alloc((size_t)XTN * 2);
    float* agg     = (float*)alloc((size_t)XTN * 4);
    float* PP      = (float*)alloc(13904 * 4);
    int2*  bucket  = (int2*) alloc((size_t)NN * CAP * 8);
    int*   cnt     = (int*)  alloc(NN * 4);   // cnt and degf adjacent: one memset
    float* degf    = (float*)alloc(NN * 4);

    const int* srcp = ei;
    const int* dstp = ei + NE;

    hipMemsetAsync(cnt, 0, 2 * NN * sizeof(int), stream);   // cnt + degf
    setup_kernel<<<(XTN + 255) / 256, 256, 0, stream>>>(x, srcp, dstp, ew, cnt, degf,
                                                        bucket, xAll,
                                                        Wz, bz, Wr, br, Wh, bh,
                                                        Lz, Lz_b, Lr, Lr_b, Lh, Lh_b,
                                                        lw, lb, PP);
    aggregate_kernel<<<NN, 128, 0, stream>>>(xAll, bucket, cnt, degf, agg);
    recurrent_kernel<<<NBROWS / 64, 256, 0, stream>>>(agg, PP, out);
}